// Round 1
// baseline (344.769 us; speedup 1.0000x reference)
//
#include <hip/hip_runtime.h>
#include <stdint.h>

typedef __attribute__((ext_vector_type(4))) int i32x4;
typedef __attribute__((ext_vector_type(8))) int i32x8;
typedef __attribute__((ext_vector_type(16))) float f32x16;

#define BM 128
#define BN 128
// K per LDS tile = 128 fp4 elements = 64 bytes per row

// fp4 e2m1 signs: +1 = 0x2, -1 = 0xA, 0 = 0x0 (matches jnp.sign exactly)
__device__ __forceinline__ uint32_t nib4(float v) {
  return v > 0.f ? 0x2u : (v < 0.f ? 0xAu : 0u);
}

// 8 fp32 -> 8 nibbles in one u32 (element j -> nibble j, low nibble first)
__device__ __forceinline__ uint32_t pack8(float4 a, float4 b) {
  return nib4(a.x) | (nib4(a.y) << 4) | (nib4(a.z) << 8) | (nib4(a.w) << 12) |
         (nib4(b.x) << 16) | (nib4(b.y) << 20) | (nib4(b.z) << 24) | (nib4(b.w) << 28);
}

// ---------------- fused quantize: x -> fp4 signs, w -> fp4 signs + mean|w| ----------------
// Blocks [0, N): one block per weight row (pack + wave-shuffle abs-sum reduction).
// Blocks [N, N+xBlocks): streaming x pack, 4 u32 outputs per thread.
// Access pattern: each thread reads 2 CONSECUTIVE float4s (32-B lane stride; the two
// back-to-back loads cover complementary halves of the same cache lines -> ~full
// coalescing density), writes one fully-coalesced u32 per pair.
__global__ __launch_bounds__(256) void quant_fused_kernel(
    const float4* __restrict__ x, uint32_t* __restrict__ xq,
    const float4* __restrict__ w, uint32_t* __restrict__ wq,
    float* __restrict__ scale, int N, int K) {
  const int t = threadIdx.x;
  const int b = blockIdx.x;

  if (b < N) {
    // ---- weight row b: K elems = K/8 u32 outputs ----
    const float4* wr = w + (size_t)b * (K / 4);
    uint32_t* wo = wq + (size_t)b * (K / 8);
    float asum = 0.f;
    for (int p = t; p < K / 8; p += 256) {
      float4 a = wr[2 * p];
      float4 c = wr[2 * p + 1];
      wo[p] = pack8(a, c);
      asum += fabsf(a.x) + fabsf(a.y) + fabsf(a.z) + fabsf(a.w) +
              fabsf(c.x) + fabsf(c.y) + fabsf(c.z) + fabsf(c.w);
    }
    // wave-level shuffle reduce (64 lanes), then cross-wave via 4-slot LDS
    for (int off = 32; off > 0; off >>= 1) asum += __shfl_down(asum, off);
    __shared__ float red[4];
    if ((t & 63) == 0) red[t >> 6] = asum;
    __syncthreads();
    if (t == 0) scale[b] = (red[0] + red[1] + red[2] + red[3]) / (float)K;
  } else {
    // ---- x chunk: 1024 u32 outputs per block, 4 per thread ----
    const size_t base = (size_t)(b - N) * 1024;  // in u32-pair units
#pragma unroll
    for (int j = 0; j < 4; ++j) {
      size_t p = base + (size_t)j * 256 + t;
      float4 a = x[2 * p];
      float4 c = x[2 * p + 1];
      xq[p] = pack8(a, c);
    }
  }
}

// async global->LDS, 16B per lane (wave-uniform base + lane*16)
__device__ __forceinline__ void load16(const uint8_t* g, uint8_t* l) {
  __builtin_amdgcn_global_load_lds(
      (const __attribute__((address_space(1))) uint32_t*)(uintptr_t)g,
      (__attribute__((address_space(3))) uint32_t*)(uintptr_t)l,
      16, 0, 0);
}

// ---------------- GEMM: C[m,n] = scale[n] * sum_k A[m,k]*B[n,k] ----------------
// A: [M,K/2] fp4-pair bytes, B: [N,K/2]. mfma_scale 32x32x64 f8f6f4, FMT=4 (fp4),
// scales pinned to 1.0 (e8m0 0x7F). fp32 accumulate is exact for +-1 sums.
// 256 threads = 4 waves in 2x2; each wave does 64x64 via 2x2 of 32x32 tiles.
__global__ __launch_bounds__(256, 3) void gemm_bt_kernel(
    const uint8_t* __restrict__ A, const uint8_t* __restrict__ B,
    const float* __restrict__ scale, float* __restrict__ C,
    int M, int N, int K) {
  __shared__ __align__(16) uint8_t As[BM * 64];  // 8 KB: 128 rows x 64 B (=128 fp4)
  __shared__ __align__(16) uint8_t Bs[BN * 64];  // 8 KB

  const int tid = threadIdx.x;
  const int lane = tid & 63;
  const int wave = tid >> 6;
  const int waveM = wave & 1;
  const int waveN = wave >> 1;

  const int rowA0 = blockIdx.y * BM;
  const int rowB0 = blockIdx.x * BN;

  const int KB = K / 2;  // row stride in bytes

  // staging: per wave 2 insts for A (16 rows each, 64 B/row = 4 lanes/row) + 2 for B
  const uint8_t* aG = A + (size_t)(rowA0 + wave * 32 + (lane >> 2)) * KB + (lane & 3) * 16;
  const uint8_t* bG = B + (size_t)(rowB0 + wave * 32 + (lane >> 2)) * KB + (lane & 3) * 16;
  uint8_t* aL = As + wave * 2048 + lane * 16;
  uint8_t* bL = Bs + wave * 2048 + lane * 16;
  const size_t strideG16 = (size_t)16 * KB;

  // fragment: lane holds row m=lane&31, K-group (lane>>5): 32 fp4 = 16 B
  const uint8_t* aF = As + (size_t)(waveM * 64 + (lane & 31)) * 64 + (lane >> 5) * 16;
  const uint8_t* bF = Bs + (size_t)(waveN * 64 + (lane & 31)) * 64 + (lane >> 5) * 16;

  f32x16 acc[2][2] = {};
  // persistent v8i32 operands; high 4 regs stay zero (fp4 uses low 4 only)
  i32x8 aop[2] = {}, bop[2] = {};

  for (int kb = 0; kb < KB; kb += 64) {
    __syncthreads();  // previous iter's LDS reads done before overwrite
    load16(aG + kb, aL);
    load16(aG + kb + strideG16, aL + 1024);
    load16(bG + kb, bL);
    load16(bG + kb + strideG16, bL + 1024);
    __syncthreads();  // staging complete (vmcnt drained before barrier)

#pragma unroll
    for (int s = 0; s < 2; ++s) {  // two K=64 MFMA steps per 64-B row tile
#pragma unroll
      for (int mi = 0; mi < 2; ++mi) {
        i32x4 t = *(const i32x4*)(aF + mi * 32 * 64 + s * 32);
        aop[mi].s0 = t.x; aop[mi].s1 = t.y; aop[mi].s2 = t.z; aop[mi].s3 = t.w;
      }
#pragma unroll
      for (int ni = 0; ni < 2; ++ni) {
        i32x4 t = *(const i32x4*)(bF + ni * 32 * 64 + s * 32);
        bop[ni].s0 = t.x; bop[ni].s1 = t.y; bop[ni].s2 = t.z; bop[ni].s3 = t.w;
      }
#pragma unroll
      for (int mi = 0; mi < 2; ++mi)
#pragma unroll
        for (int ni = 0; ni < 2; ++ni)
          acc[mi][ni] = __builtin_amdgcn_mfma_scale_f32_32x32x64_f8f6f4(
              aop[mi], bop[ni], acc[mi][ni],
              /*cbsz=fp4*/ 4, /*blgp=fp4*/ 4,
              /*opsel_a*/ 0, 0x7f7f7f7f, /*opsel_b*/ 0, 0x7f7f7f7f);
    }
  }

  // epilogue: 32x32 C/D layout col=lane&31, row=(reg&3)+8*(reg>>2)+4*(lane>>5)
  // (HW-verified, dtype-independent)
  const int cCol = rowB0 + waveN * 64 + (lane & 31);
  const int cRowBase = rowA0 + waveM * 64 + 4 * (lane >> 5);
  float sc[2];
#pragma unroll
  for (int ni = 0; ni < 2; ++ni) sc[ni] = scale[cCol + ni * 32];
#pragma unroll
  for (int mi = 0; mi < 2; ++mi)
#pragma unroll
    for (int ni = 0; ni < 2; ++ni)
#pragma unroll
      for (int r = 0; r < 16; ++r) {
        int row = cRowBase + mi * 32 + (r & 3) + 8 * (r >> 2);
        C[(size_t)row * N + cCol + ni * 32] = acc[mi][ni][r] * sc[ni];
      }
}

// ---------------- fallback (only if ws too small): exact, slow ----------------
__global__ void fallback_gemm(const float* __restrict__ X, const float* __restrict__ W,
                              float* __restrict__ C, int M, int N, int K) {
  __shared__ float xs[16][65];
  __shared__ float ws[16][65];
  __shared__ float wabs[256];
  __shared__ float scl[16];
  const int tx = threadIdx.x, ty = threadIdx.y;
  const int t = ty * 16 + tx;
  float acc = 0.f, wa = 0.f;
  for (int k0 = 0; k0 < K; k0 += 64) {
    __syncthreads();
#pragma unroll
    for (int j = 0; j < 4; ++j) {
      int e = t * 4 + j;
      int r = e >> 6, c = e & 63;
      float xv = X[(size_t)(blockIdx.y * 16 + r) * K + k0 + c];
      xs[r][c] = xv > 0.f ? 1.f : (xv < 0.f ? -1.f : 0.f);
      float wv = W[(size_t)(blockIdx.x * 16 + r) * K + k0 + c];
      ws[r][c] = wv > 0.f ? 1.f : (wv < 0.f ? -1.f : 0.f);
      wa += fabsf(wv);
    }
    __syncthreads();
#pragma unroll 8
    for (int k = 0; k < 64; ++k) acc += xs[ty][k] * ws[tx][k];
  }
  wabs[t] = wa;
  __syncthreads();
  for (int s2 = 8; s2 > 0; s2 >>= 1) {
    if (tx < s2) wabs[t] += wabs[t + s2];
    __syncthreads();
  }
  if (tx == 0) scl[ty] = wabs[t] / (float)K;
  __syncthreads();
  C[(size_t)(blockIdx.y * 16 + ty) * N + (blockIdx.x * 16 + tx)] = acc * scl[tx];
}

extern "C" void kernel_launch(void* const* d_in, const int* in_sizes, int n_in,
                              void* d_out, int out_size, void* d_ws, size_t ws_size,
                              hipStream_t stream) {
  const float* x = (const float*)d_in[0];
  const float* w = (const float*)d_in[1];
  float* out = (float*)d_out;

  const int K = 4096;
  const int N = in_sizes[1] / K;  // 4096
  const int M = in_sizes[0] / K;  // 8192

  size_t need = (size_t)M * (K / 2) + (size_t)N * (K / 2) + (size_t)N * sizeof(float);
  if (ws_size >= need) {
    uint8_t* Xq = (uint8_t*)d_ws;
    uint8_t* Wq = Xq + (size_t)M * (K / 2);
    float* scale = (float*)(Wq + (size_t)N * (K / 2));

    // fused quant: N blocks for weight rows + M*K/8192 blocks for x (1024 u32 per block)
    const int xBlocks = (int)(((size_t)M * K) / 8192);
    quant_fused_kernel<<<N + xBlocks, 256, 0, stream>>>(
        (const float4*)x, (uint32_t*)Xq, (const float4*)w, (uint32_t*)Wq, scale, N, K);

    dim3 grid(N / BN, M / BM);
    gemm_bt_kernel<<<grid, 256, 0, stream>>>(Xq, Wq, scale, out, M, N, K);
  } else {
    dim3 grid(N / 16, M / 16);
    fallback_gemm<<<grid, dim3(16, 16), 0, stream>>>(x, w, out, M, N, K);
  }
}